// Round 15
// baseline (9827.798 us; speedup 1.0000x reference)
//
#include <hip/hip_runtime.h>

#define T_STEPS 1024
#define BSZ 256
#define HD 256
#define OUTC 64
#define WSTEPS 16
#define NWIN (T_STEPS / WSTEPS)
#define WREG 48   // k-quads of Wi2h h-part in registers (C phase)
#define WTAIL 16  // k-quads of Wi2h h-part in LDS

// ---------------- ws layout (float offsets) ----------------
static const size_t OFF_SUM  = 0;        // [256][256] f32  (Sum_t outs)
static const size_t OFF_FLAG = 65536;    // int flag (x is int64?)
static const size_t OFF_WP   = 65792;    // 3 x [128][256] float4 packed weights

// x-dtype detector: if x is int64, all sampled high 32-bit words are zero.
__global__ void detect_x(const int* __restrict__ x, float* __restrict__ ws) {
    __shared__ int nonzero;
    if (threadIdx.x == 0) nonzero = 0;
    __syncthreads();
    if (x[2 * threadIdx.x + 1] != 0) nonzero = 1;   // benign same-value race
    __syncthreads();
    if (threadIdx.x == 0) *(int*)(ws + OFF_FLAG) = (nonzero == 0) ? 1 : 0;
}

// Pack weights as float4 per (k-quad, column): Wp[z][q][j] = {W_z[j][4q+c]}.
// Values identical to source -> FMA chains stay bit-identical.
__global__ void prep_pack(const float* __restrict__ Wi2h,
                          const float* __restrict__ Wi2o,
                          const float* __restrict__ Wo2o,
                          float* __restrict__ ws) {
    const int q = blockIdx.x;            // 0..127 (k quad)
    const int z = blockIdx.y;            // 0..2
    const int j = threadIdx.x;           // 0..255 (column)
    const float* src = (z == 0) ? Wi2h : (z == 1) ? Wi2o : Wo2o;
    const float4 v = *reinterpret_cast<const float4*>(src + (size_t)j * 512 + 4 * q);
    reinterpret_cast<float4*>(ws + OFF_WP)[((size_t)z * 128 + q) * 256 + j] = v;
}

// exact-bit wave broadcast: value of v at lane l
__device__ __forceinline__ float RLf(float v, int l) {
    return __int_as_float(__builtin_amdgcn_readlane(__float_as_int(v), l));
}

// Bit-faithful f32 scan, two-wave-group version.
// 256 blocks x 512 threads; 1 batch row per block. Thread (grp, j) owns
// column j; group g handles window-steps t = 8g..8g+7 in the t-parallel
// phases (B, D2, D). C (the truly sequential 16 steps) runs on group 0 only
// while group 1 parks at the barriers. The t-ascending f32 fold of Sum_t is
// preserved exactly: group 1 ships raw a2 via LDS, group 0 folds t=0..15 in
// order with the identical (a2 + boo_j) adds. All per-element fmaf chains
// are the identical k-ascending sequences of the validated R7 kernel.
__global__ __launch_bounds__(512, 2) void scan_all(
    const int* __restrict__ x, const float* __restrict__ emb,
    const float* __restrict__ bih, const float* __restrict__ bio,
    const float* __restrict__ boo, float* __restrict__ ws) {
    const int tid = threadIdx.x;
    const int j = tid & 255;            // column
    const int lane = tid & 63;
    const int grp = tid >> 8;           // wave group 0/1
    const int tbase = grp * 8;          // group's first t in window
    const int row = blockIdx.x;
    const int mode64 = *(const int*)(ws + OFF_FLAG);

    const float4* __restrict__ Wh4  = reinterpret_cast<const float4*>(ws + OFF_WP);
    const float4* __restrict__ Wio4 = Wh4 + (size_t)128 * 256;
    const float4* __restrict__ Woo4 = Wh4 + (size_t)256 * 256;

    __shared__ __align__(16) float eW[WSTEPS][256];        // 16 KB
    __shared__ __align__(16) float hHist[WSTEPS + 1][256]; // 17 KB
    __shared__ __align__(16) float oHist[WSTEPS][256];     // 16 KB
    __shared__ float aHb[WSTEPS][256];                     // 16 KB (also a2 hop)
    __shared__ float aOb[WSTEPS][256];                     // 16 KB
    __shared__ float wTail[WTAIL][4][256];                 // 64 KB
    __shared__ int toks[WSTEPS];
    // total ~145 KB -> 1 block/CU, 8 waves = 2/SIMD

    // stage Wi2h h-part tail quads (k-quads 64+WREG..127); group g stages 8
    #pragma unroll
    for (int k = 0; k < 8; ++k) {
        const int qq = tbase + k;
        const float4 v = Wh4[(size_t)(64 + WREG + qq) * 256 + j];
        wTail[qq][0][j] = v.x; wTail[qq][1][j] = v.y;
        wTail[qq][2][j] = v.z; wTail[qq][3][j] = v.w;
    }

    const float bih_j = bih[j], bio_j = bio[j], boo_j = boo[j];
    float sum = 0.f;                    // meaningful for grp 0 only
    if (tid < 256) hHist[WSTEPS][j] = 0.f;   // h_0 = 0 seed (slot 16)
    __syncthreads();

    #pragma unroll 1
    for (int w = 0; w < NWIN; ++w) {
        // ---- A: tokens; carry h (slot16 -> slot0); stage e rows
        if (tid < WSTEPS) {
            const int idx = (w * WSTEPS + tid) * BSZ + row;
            toks[tid] = mode64 ? x[2 * idx] : x[idx];
        }
        if (tid < 256) hHist[0][j] = hHist[WSTEPS][j];
        __syncthreads();
        #pragma unroll
        for (int u = 0; u < 8; ++u)
            eW[tbase + u][j] = emb[(size_t)toks[tbase + u] * HD + j];
        __syncthreads();

        // ---- B: e-part chains (k = 0..255) for this group's 8 t's
        float aH[8], aO[8];
        #pragma unroll
        for (int u = 0; u < 8; ++u) { aH[u] = 0.f; aO[u] = 0.f; }
        #pragma unroll 2
        for (int q = 0; q < 64; ++q) {
            const float4 wh = Wh4[(size_t)q * 256 + j];
            const float4 wo = Wio4[(size_t)q * 256 + j];
            #pragma unroll
            for (int u = 0; u < 8; ++u) {
                const float4 e = *reinterpret_cast<const float4*>(&eW[tbase + u][4 * q]);
                float h = aH[u], o = aO[u];
                h = fmaf(e.x, wh.x, h); o = fmaf(e.x, wo.x, o);
                h = fmaf(e.y, wh.y, h); o = fmaf(e.y, wo.y, o);
                h = fmaf(e.z, wh.z, h); o = fmaf(e.z, wo.z, o);
                h = fmaf(e.w, wh.w, h); o = fmaf(e.w, wo.w, o);
                aH[u] = h; aO[u] = o;
            }
        }
        #pragma unroll
        for (int u = 0; u < 8; ++u) {
            aHb[tbase + u][j] = aH[u];   // own slot: exact f32 hop
            aOb[tbase + u][j] = aO[u];
        }

        // ---- C: 16 sequential steps (group 0 only; group 1 parks)
        {
            float4 whr[WREG];
            if (grp == 0) {
                #pragma unroll
                for (int qq = 0; qq < WREG; ++qq)
                    whr[qq] = Wh4[(size_t)(64 + qq) * 256 + j];
            }
            #pragma unroll 1
            for (int t = 0; t < WSTEPS; ++t) {
                __syncthreads();          // hHist[t] + (t=0: aHb both groups)
                if (grp == 0) {
                    const float4 h4 = *reinterpret_cast<const float4*>(&hHist[t][4 * lane]);
                    float ah = aHb[t][j];
                    #pragma unroll
                    for (int qq = 0; qq < WREG; ++qq) {
                        ah = fmaf(RLf(h4.x, qq), whr[qq].x, ah);
                        ah = fmaf(RLf(h4.y, qq), whr[qq].y, ah);
                        ah = fmaf(RLf(h4.z, qq), whr[qq].z, ah);
                        ah = fmaf(RLf(h4.w, qq), whr[qq].w, ah);
                    }
                    #pragma unroll
                    for (int qq = 0; qq < WTAIL; ++qq) {
                        const int l = WREG + qq;
                        ah = fmaf(RLf(h4.x, l), wTail[qq][0][j], ah);
                        ah = fmaf(RLf(h4.y, l), wTail[qq][1][j], ah);
                        ah = fmaf(RLf(h4.z, l), wTail[qq][2][j], ah);
                        ah = fmaf(RLf(h4.w, l), wTail[qq][3][j], ah);
                    }
                    hHist[t + 1][j] = ah + bih_j;   // + b_i2h
                }
            }
            __syncthreads();              // all h states published
        }

        // ---- D2: o's h-part (k = 256..511) for group's 8 t's
        {
            float4 hv[8]; float aOr[8];
            #pragma unroll
            for (int u = 0; u < 8; ++u) {
                hv[u] = *reinterpret_cast<const float4*>(&hHist[tbase + u][4 * lane]);
                aOr[u] = aOb[tbase + u][j];
            }
            #pragma unroll 2
            for (int q = 0; q < 64; ++q) {
                const float4 w4 = Wio4[(size_t)(64 + q) * 256 + j];
                #pragma unroll
                for (int u = 0; u < 8; ++u) {
                    float s;
                    s = RLf(hv[u].x, q); aOr[u] = fmaf(s, w4.x, aOr[u]);
                    s = RLf(hv[u].y, q); aOr[u] = fmaf(s, w4.y, aOr[u]);
                    s = RLf(hv[u].z, q); aOr[u] = fmaf(s, w4.z, aOr[u]);
                    s = RLf(hv[u].w, q); aOr[u] = fmaf(s, w4.w, aOr[u]);
                }
            }
            #pragma unroll
            for (int u = 0; u < 8; ++u)
                oHist[tbase + u][j] = aOr[u] + bio_j;    // + b_i2o
        }
        __syncthreads();                 // o published

        // ---- D: out-chains for group's 8 t's (hn part, then o part)
        float a2[8];
        #pragma unroll
        for (int u = 0; u < 8; ++u) a2[u] = 0.f;
        {
            float4 hv[8];
            #pragma unroll
            for (int u = 0; u < 8; ++u)
                hv[u] = *reinterpret_cast<const float4*>(&hHist[tbase + u + 1][4 * lane]);
            #pragma unroll 2
            for (int q = 0; q < 64; ++q) {
                const float4 w4 = Woo4[(size_t)q * 256 + j];
                #pragma unroll
                for (int u = 0; u < 8; ++u) {
                    float s;
                    s = RLf(hv[u].x, q); a2[u] = fmaf(s, w4.x, a2[u]);
                    s = RLf(hv[u].y, q); a2[u] = fmaf(s, w4.y, a2[u]);
                    s = RLf(hv[u].z, q); a2[u] = fmaf(s, w4.z, a2[u]);
                    s = RLf(hv[u].w, q); a2[u] = fmaf(s, w4.w, a2[u]);
                }
            }
            float4 ov[8];
            #pragma unroll
            for (int u = 0; u < 8; ++u)
                ov[u] = *reinterpret_cast<const float4*>(&oHist[tbase + u][4 * lane]);
            #pragma unroll 2
            for (int q = 0; q < 64; ++q) {
                const float4 w4 = Woo4[(size_t)(64 + q) * 256 + j];
                #pragma unroll
                for (int u = 0; u < 8; ++u) {
                    float s;
                    s = RLf(ov[u].x, q); a2[u] = fmaf(s, w4.x, a2[u]);
                    s = RLf(ov[u].y, q); a2[u] = fmaf(s, w4.y, a2[u]);
                    s = RLf(ov[u].z, q); a2[u] = fmaf(s, w4.z, a2[u]);
                    s = RLf(ov[u].w, q); a2[u] = fmaf(s, w4.w, a2[u]);
                }
            }
        }

        // ---- fold: strict t-ascending order across both groups
        if (grp == 1) {
            #pragma unroll
            for (int u = 0; u < 8; ++u) aHb[u][j] = a2[u];   // raw a2, t=8+u
        }
        __syncthreads();
        if (grp == 0) {
            #pragma unroll
            for (int u = 0; u < 8; ++u) sum += (a2[u] + boo_j);       // t=0..7
            #pragma unroll
            for (int u = 0; u < 8; ++u) sum += (aHb[u][j] + boo_j);   // t=8..15
        }
        // next A's writes (toks, hHist[0]) are grp0-only and happen after its
        // fold; eW staging is gated by A's barrier; aHb rewritten in next B
        // only after the eW barrier. No cross-window races.
    }

    if (tid < 256) ws[OFF_SUM + (size_t)row * 256 + j] = sum;
}

// encoded = Sum/1024 (exact); logits = seq-k FMA + b_pred; log_softmax with
// f64-CR exp/log; first-index argmax over f32 lp.
__global__ __launch_bounds__(64) void final_k(
    const float* __restrict__ Wpred, const float* __restrict__ bpred,
    const float* __restrict__ ws, float* __restrict__ out) {
    const int b = blockIdx.x, o = threadIdx.x;
    __shared__ float enc[256];
    __shared__ float exs[64];
    __shared__ float s32s;

    #pragma unroll
    for (int u = 0; u < 4; ++u)
        enc[o * 4 + u] = ws[OFF_SUM + (size_t)b * 256 + o * 4 + u] * (1.0f / 1024.0f);
    __syncthreads();

    float acc = 0.f;
    for (int e = 0; e < 256; ++e)
        acc = fmaf(enc[e], Wpred[(size_t)o * 256 + e], acc);
    acc += bpred[o];                      // logits[b][o], f32

    float m = acc;
    #pragma unroll
    for (int d = 1; d < 64; d <<= 1) m = fmaxf(m, __shfl_xor(m, d));
    const float sh = acc - m;
    const float ex = (float)exp((double)sh);
    exs[o] = ex;
    __syncthreads();
    if (o == 0) {
        double sd = 0.0;
        for (int i = 0; i < 64; ++i) sd += (double)exs[i];
        s32s = (float)sd;
    }
    __syncthreads();
    const float log_s = (float)log((double)s32s);
    const float lp = sh - log_s;
    const float pr = (float)exp((double)lp);

    float av = lp; int ai = o;
    #pragma unroll
    for (int d = 1; d < 64; d <<= 1) {
        const float ov = __shfl_xor(av, d);
        const int oi = __shfl_xor(ai, d);
        if (ov > av || (ov == av && oi < ai)) { av = ov; ai = oi; }
    }

    out[BSZ + (size_t)b * OUTC + o] = lp;              // logprobs
    out[BSZ + 16384 + (size_t)b * OUTC + o] = pr;      // probs
    if (o == 0) out[b] = (float)ai;                    // preds
}

// ---------------- host ----------------
extern "C" void kernel_launch(void* const* d_in, const int* in_sizes, int n_in,
                              void* d_out, int out_size, void* d_ws, size_t ws_size,
                              hipStream_t stream) {
    const int*   x     = (const int*)d_in[0];
    const float* emb   = (const float*)d_in[1];
    const float* Wi2h  = (const float*)d_in[2];
    const float* b_ih  = (const float*)d_in[3];
    const float* Wi2o  = (const float*)d_in[4];
    const float* b_io  = (const float*)d_in[5];
    const float* Wo2o  = (const float*)d_in[6];
    const float* b_oo  = (const float*)d_in[7];
    const float* Wpred = (const float*)d_in[8];
    const float* b_p   = (const float*)d_in[9];
    float* ws  = (float*)d_ws;
    float* out = (float*)d_out;

    detect_x<<<1, 256, 0, stream>>>(x, ws);
    prep_pack<<<dim3(128, 3), 256, 0, stream>>>(Wi2h, Wi2o, Wo2o, ws);
    scan_all<<<dim3(256), 512, 0, stream>>>(x, emb, b_ih, b_io, b_oo, ws);
    final_k<<<dim3(256), 64, 0, stream>>>(Wpred, b_p, ws, out);
}

// Round 16
// 9822.037 us; speedup vs baseline: 1.0006x; 1.0006x over previous
//
#include <hip/hip_runtime.h>

#define T_STEPS 1024
#define BSZ 256
#define HD 256
#define OUTC 64
#define WSTEPS 16
#define NWIN (T_STEPS / WSTEPS)
#define WREG 48   // k-quads of Wi2h h-part in registers (C phase)
#define WTAIL 16  // k-quads of Wi2h h-part in LDS

// ---------------- ws layout (float offsets) ----------------
static const size_t OFF_SUM  = 0;        // [256][256] f32  (Sum_t outs)
static const size_t OFF_FLAG = 65536;    // int flag (x is int64?)
static const size_t OFF_WP   = 65792;    // 3 x [128][256] float4 packed weights

// x-dtype detector: if x is int64, all sampled high 32-bit words are zero.
__global__ void detect_x(const int* __restrict__ x, float* __restrict__ ws) {
    __shared__ int nonzero;
    if (threadIdx.x == 0) nonzero = 0;
    __syncthreads();
    if (x[2 * threadIdx.x + 1] != 0) nonzero = 1;   // benign same-value race
    __syncthreads();
    if (threadIdx.x == 0) *(int*)(ws + OFF_FLAG) = (nonzero == 0) ? 1 : 0;
}

// Pack weights as float4 per (k-quad, column): Wp[z][q][j] = {W_z[j][4q+c]}.
// Values identical to source -> FMA chains stay bit-identical.
__global__ void prep_pack(const float* __restrict__ Wi2h,
                          const float* __restrict__ Wi2o,
                          const float* __restrict__ Wo2o,
                          float* __restrict__ ws) {
    const int q = blockIdx.x;            // 0..127 (k quad)
    const int z = blockIdx.y;            // 0..2
    const int j = threadIdx.x;           // 0..255 (column)
    const float* src = (z == 0) ? Wi2h : (z == 1) ? Wi2o : Wo2o;
    const float4 v = *reinterpret_cast<const float4*>(src + (size_t)j * 512 + 4 * q);
    reinterpret_cast<float4*>(ws + OFF_WP)[((size_t)z * 128 + q) * 256 + j] = v;
}

// exact-bit wave broadcast: value of v at lane l
__device__ __forceinline__ float RLf(float v, int l) {
    return __int_as_float(__builtin_amdgcn_readlane(__float_as_int(v), l));
}

// Bit-faithful f32 scan, two-wave-group version (uncapped registers).
// 256 blocks x 512 threads; 1 batch row per block. Thread (grp, j) owns
// column j; group g handles window-steps t = 8g..8g+7 in the t-parallel
// phases (B, D2, D). C (the truly sequential 16 steps) runs on group 0 only
// while group 1 parks at the barriers. The t-ascending f32 fold of Sum_t is
// preserved exactly: group 1 ships raw a2 via LDS, group 0 folds t=0..15 in
// order with the identical (a2 + boo_j) adds. All per-element fmaf chains
// are the identical k-ascending sequences of the validated R7 kernel.
__global__ __launch_bounds__(512) void scan_all(
    const int* __restrict__ x, const float* __restrict__ emb,
    const float* __restrict__ bih, const float* __restrict__ bio,
    const float* __restrict__ boo, float* __restrict__ ws) {
    const int tid = threadIdx.x;
    const int j = tid & 255;            // column
    const int lane = tid & 63;
    const int grp = tid >> 8;           // wave group 0/1
    const int tbase = grp * 8;          // group's first t in window
    const int row = blockIdx.x;
    const int mode64 = *(const int*)(ws + OFF_FLAG);

    const float4* __restrict__ Wh4  = reinterpret_cast<const float4*>(ws + OFF_WP);
    const float4* __restrict__ Wio4 = Wh4 + (size_t)128 * 256;
    const float4* __restrict__ Woo4 = Wh4 + (size_t)256 * 256;

    __shared__ __align__(16) float eW[WSTEPS][256];        // 16 KB
    __shared__ __align__(16) float hHist[WSTEPS + 1][256]; // 17 KB
    __shared__ __align__(16) float oHist[WSTEPS][256];     // 16 KB
    __shared__ float aHb[WSTEPS][256];                     // 16 KB (also a2 hop)
    __shared__ float aOb[WSTEPS][256];                     // 16 KB
    __shared__ float wTail[WTAIL][4][256];                 // 64 KB
    __shared__ int toks[WSTEPS];
    // total ~145 KB -> 1 block/CU, 8 waves = 2/SIMD

    // stage Wi2h h-part tail quads (k-quads 64+WREG..127); group g stages 8
    #pragma unroll
    for (int k = 0; k < 8; ++k) {
        const int qq = tbase + k;
        const float4 v = Wh4[(size_t)(64 + WREG + qq) * 256 + j];
        wTail[qq][0][j] = v.x; wTail[qq][1][j] = v.y;
        wTail[qq][2][j] = v.z; wTail[qq][3][j] = v.w;
    }

    const float bih_j = bih[j], bio_j = bio[j], boo_j = boo[j];
    float sum = 0.f;                    // meaningful for grp 0 only
    if (tid < 256) hHist[WSTEPS][j] = 0.f;   // h_0 = 0 seed (slot 16)
    __syncthreads();

    #pragma unroll 1
    for (int w = 0; w < NWIN; ++w) {
        // ---- A: tokens; carry h (slot16 -> slot0); stage e rows
        if (tid < WSTEPS) {
            const int idx = (w * WSTEPS + tid) * BSZ + row;
            toks[tid] = mode64 ? x[2 * idx] : x[idx];
        }
        if (tid < 256) hHist[0][j] = hHist[WSTEPS][j];
        __syncthreads();
        #pragma unroll
        for (int u = 0; u < 8; ++u)
            eW[tbase + u][j] = emb[(size_t)toks[tbase + u] * HD + j];
        __syncthreads();

        // ---- B: e-part chains (k = 0..255) for this group's 8 t's
        float aH[8], aO[8];
        #pragma unroll
        for (int u = 0; u < 8; ++u) { aH[u] = 0.f; aO[u] = 0.f; }
        #pragma unroll 2
        for (int q = 0; q < 64; ++q) {
            const float4 wh = Wh4[(size_t)q * 256 + j];
            const float4 wo = Wio4[(size_t)q * 256 + j];
            #pragma unroll
            for (int u = 0; u < 8; ++u) {
                const float4 e = *reinterpret_cast<const float4*>(&eW[tbase + u][4 * q]);
                float h = aH[u], o = aO[u];
                h = fmaf(e.x, wh.x, h); o = fmaf(e.x, wo.x, o);
                h = fmaf(e.y, wh.y, h); o = fmaf(e.y, wo.y, o);
                h = fmaf(e.z, wh.z, h); o = fmaf(e.z, wo.z, o);
                h = fmaf(e.w, wh.w, h); o = fmaf(e.w, wo.w, o);
                aH[u] = h; aO[u] = o;
            }
        }
        #pragma unroll
        for (int u = 0; u < 8; ++u) {
            aHb[tbase + u][j] = aH[u];   // own slot: exact f32 hop
            aOb[tbase + u][j] = aO[u];
        }

        // ---- C: 16 sequential steps (group 0 only; group 1 parks)
        {
            float4 whr[WREG];
            if (grp == 0) {
                #pragma unroll
                for (int qq = 0; qq < WREG; ++qq)
                    whr[qq] = Wh4[(size_t)(64 + qq) * 256 + j];
            }
            #pragma unroll 1
            for (int t = 0; t < WSTEPS; ++t) {
                __syncthreads();          // hHist[t] + (t=0: aHb both groups)
                if (grp == 0) {
                    const float4 h4 = *reinterpret_cast<const float4*>(&hHist[t][4 * lane]);
                    float ah = aHb[t][j];
                    #pragma unroll
                    for (int qq = 0; qq < WREG; ++qq) {
                        ah = fmaf(RLf(h4.x, qq), whr[qq].x, ah);
                        ah = fmaf(RLf(h4.y, qq), whr[qq].y, ah);
                        ah = fmaf(RLf(h4.z, qq), whr[qq].z, ah);
                        ah = fmaf(RLf(h4.w, qq), whr[qq].w, ah);
                    }
                    #pragma unroll
                    for (int qq = 0; qq < WTAIL; ++qq) {
                        const int l = WREG + qq;
                        ah = fmaf(RLf(h4.x, l), wTail[qq][0][j], ah);
                        ah = fmaf(RLf(h4.y, l), wTail[qq][1][j], ah);
                        ah = fmaf(RLf(h4.z, l), wTail[qq][2][j], ah);
                        ah = fmaf(RLf(h4.w, l), wTail[qq][3][j], ah);
                    }
                    hHist[t + 1][j] = ah + bih_j;   // + b_i2h
                }
            }
            __syncthreads();              // all h states published
        }

        // ---- D2: o's h-part (k = 256..511) for group's 8 t's
        {
            float4 hv[8]; float aOr[8];
            #pragma unroll
            for (int u = 0; u < 8; ++u) {
                hv[u] = *reinterpret_cast<const float4*>(&hHist[tbase + u][4 * lane]);
                aOr[u] = aOb[tbase + u][j];
            }
            #pragma unroll 2
            for (int q = 0; q < 64; ++q) {
                const float4 w4 = Wio4[(size_t)(64 + q) * 256 + j];
                #pragma unroll
                for (int u = 0; u < 8; ++u) {
                    float s;
                    s = RLf(hv[u].x, q); aOr[u] = fmaf(s, w4.x, aOr[u]);
                    s = RLf(hv[u].y, q); aOr[u] = fmaf(s, w4.y, aOr[u]);
                    s = RLf(hv[u].z, q); aOr[u] = fmaf(s, w4.z, aOr[u]);
                    s = RLf(hv[u].w, q); aOr[u] = fmaf(s, w4.w, aOr[u]);
                }
            }
            #pragma unroll
            for (int u = 0; u < 8; ++u)
                oHist[tbase + u][j] = aOr[u] + bio_j;    // + b_i2o
        }
        __syncthreads();                 // o published

        // ---- D: out-chains for group's 8 t's (hn part, then o part)
        float a2[8];
        #pragma unroll
        for (int u = 0; u < 8; ++u) a2[u] = 0.f;
        {
            float4 hv[8];
            #pragma unroll
            for (int u = 0; u < 8; ++u)
                hv[u] = *reinterpret_cast<const float4*>(&hHist[tbase + u + 1][4 * lane]);
            #pragma unroll 2
            for (int q = 0; q < 64; ++q) {
                const float4 w4 = Woo4[(size_t)q * 256 + j];
                #pragma unroll
                for (int u = 0; u < 8; ++u) {
                    float s;
                    s = RLf(hv[u].x, q); a2[u] = fmaf(s, w4.x, a2[u]);
                    s = RLf(hv[u].y, q); a2[u] = fmaf(s, w4.y, a2[u]);
                    s = RLf(hv[u].z, q); a2[u] = fmaf(s, w4.z, a2[u]);
                    s = RLf(hv[u].w, q); a2[u] = fmaf(s, w4.w, a2[u]);
                }
            }
            float4 ov[8];
            #pragma unroll
            for (int u = 0; u < 8; ++u)
                ov[u] = *reinterpret_cast<const float4*>(&oHist[tbase + u][4 * lane]);
            #pragma unroll 2
            for (int q = 0; q < 64; ++q) {
                const float4 w4 = Woo4[(size_t)(64 + q) * 256 + j];
                #pragma unroll
                for (int u = 0; u < 8; ++u) {
                    float s;
                    s = RLf(ov[u].x, q); a2[u] = fmaf(s, w4.x, a2[u]);
                    s = RLf(ov[u].y, q); a2[u] = fmaf(s, w4.y, a2[u]);
                    s = RLf(ov[u].z, q); a2[u] = fmaf(s, w4.z, a2[u]);
                    s = RLf(ov[u].w, q); a2[u] = fmaf(s, w4.w, a2[u]);
                }
            }
        }

        // ---- fold: strict t-ascending order across both groups
        if (grp == 1) {
            #pragma unroll
            for (int u = 0; u < 8; ++u) aHb[u][j] = a2[u];   // raw a2, t=8+u
        }
        __syncthreads();
        if (grp == 0) {
            #pragma unroll
            for (int u = 0; u < 8; ++u) sum += (a2[u] + boo_j);       // t=0..7
            #pragma unroll
            for (int u = 0; u < 8; ++u) sum += (aHb[u][j] + boo_j);   // t=8..15
        }
        // next A's writes (toks, hHist[0]) are grp0-only and happen after its
        // fold; eW staging is gated by A's barrier; aHb rewritten in next B
        // only after the eW barrier. No cross-window races.
    }

    if (tid < 256) ws[OFF_SUM + (size_t)row * 256 + j] = sum;
}

// encoded = Sum/1024 (exact); logits = seq-k FMA + b_pred; log_softmax with
// f64-CR exp/log; first-index argmax over f32 lp.
__global__ __launch_bounds__(64) void final_k(
    const float* __restrict__ Wpred, const float* __restrict__ bpred,
    const float* __restrict__ ws, float* __restrict__ out) {
    const int b = blockIdx.x, o = threadIdx.x;
    __shared__ float enc[256];
    __shared__ float exs[64];
    __shared__ float s32s;

    #pragma unroll
    for (int u = 0; u < 4; ++u)
        enc[o * 4 + u] = ws[OFF_SUM + (size_t)b * 256 + o * 4 + u] * (1.0f / 1024.0f);
    __syncthreads();

    float acc = 0.f;
    for (int e = 0; e < 256; ++e)
        acc = fmaf(enc[e], Wpred[(size_t)o * 256 + e], acc);
    acc += bpred[o];                      // logits[b][o], f32

    float m = acc;
    #pragma unroll
    for (int d = 1; d < 64; d <<= 1) m = fmaxf(m, __shfl_xor(m, d));
    const float sh = acc - m;
    const float ex = (float)exp((double)sh);
    exs[o] = ex;
    __syncthreads();
    if (o == 0) {
        double sd = 0.0;
        for (int i = 0; i < 64; ++i) sd += (double)exs[i];
        s32s = (float)sd;
    }
    __syncthreads();
    const float log_s = (float)log((double)s32s);
    const float lp = sh - log_s;
    const float pr = (float)exp((double)lp);

    float av = lp; int ai = o;
    #pragma unroll
    for (int d = 1; d < 64; d <<= 1) {
        const float ov = __shfl_xor(av, d);
        const int oi = __shfl_xor(ai, d);
        if (ov > av || (ov == av && oi < ai)) { av = ov; ai = oi; }
    }

    out[BSZ + (size_t)b * OUTC + o] = lp;              // logprobs
    out[BSZ + 16384 + (size_t)b * OUTC + o] = pr;      // probs
    if (o == 0) out[b] = (float)ai;                    // preds
}

// ---------------- host ----------------
extern "C" void kernel_launch(void* const* d_in, const int* in_sizes, int n_in,
                              void* d_out, int out_size, void* d_ws, size_t ws_size,
                              hipStream_t stream) {
    const int*   x     = (const int*)d_in[0];
    const float* emb   = (const float*)d_in[1];
    const float* Wi2h  = (const float*)d_in[2];
    const float* b_ih  = (const float*)d_in[3];
    const float* Wi2o  = (const float*)d_in[4];
    const float* b_io  = (const float*)d_in[5];
    const float* Wo2o  = (const float*)d_in[6];
    const float* b_oo  = (const float*)d_in[7];
    const float* Wpred = (const float*)d_in[8];
    const float* b_p   = (const float*)d_in[9];
    float* ws  = (float*)d_ws;
    float* out = (float*)d_out;

    detect_x<<<1, 256, 0, stream>>>(x, ws);
    prep_pack<<<dim3(128, 3), 256, 0, stream>>>(Wi2h, Wi2o, Wo2o, ws);
    scan_all<<<dim3(256), 512, 0, stream>>>(x, emb, b_ih, b_io, b_oo, ws);
    final_k<<<dim3(256), 64, 0, stream>>>(Wpred, b_p, ws, out);
}